// Round 14
// baseline (125.822 us; speedup 1.0000x reference)
//
#include <hip/hip_runtime.h>

#define D 128
#define EDIM 64
#define TDIM 64
#define KTOT 256
#define NP 5
#define LN_EPS 1e-4f
#define WSB_OFF 33024   // float offset of bf16 B-fragments in ws

typedef float v4f __attribute__((ext_vector_type(4)));
typedef float f32x4 __attribute__((ext_vector_type(4)));
typedef short bf16x8 __attribute__((ext_vector_type(8)));

__device__ __forceinline__ float clipf(float x, float lo, float hi) {
    return fminf(fmaxf(x, lo), hi);
}

__device__ __forceinline__ unsigned short bf16rne(float x) {
    unsigned int u = __float_as_uint(x);
    unsigned int r = (u + 0x7fffu + ((u >> 16) & 1u)) >> 16;
    return (unsigned short)r;
}
__device__ __forceinline__ float bf16tof(unsigned short h) {
    return __uint_as_float(((unsigned int)h) << 16);
}

// sum across each 16-lane DPP row — pure-VALU DPP reduction.
template <int CTRL>
__device__ __forceinline__ float dpp_addstep(float v) {
    int o = __builtin_amdgcn_update_dpp(0, __float_as_int(v), CTRL, 0xF, 0xF, true);
    return v + __int_as_float(o);
}
__device__ __forceinline__ float qred16(float v) {
    v = dpp_addstep<0xB1>(v);    // quad_perm xor 1
    v = dpp_addstep<0x4E>(v);    // quad_perm xor 2
    v = dpp_addstep<0x124>(v);   // row_ror:4
    v = dpp_addstep<0x128>(v);   // row_ror:8
    return v;
}

// ---------------- K0: fold weights into ws ----------------
// ws layout (floats): Wt[256*128] (k-major), c0[128], cc[3]={sgg,sgb,sbb},
// then at WSB_OFF: bf16x8 B-fragments [kb(8)][nt(8)][s(2)][lane(64)].
__global__ void k0_fold(const float* __restrict__ qw, const float* __restrict__ qb,
                        const float* __restrict__ ew, const float* __restrict__ eb,
                        const float* __restrict__ pg, const float* __restrict__ pb,
                        float* __restrict__ ws) {
    const int d = threadIdx.x;   // 0..127
    const int bk = blockIdx.x;   // 0..257
    float* Wt = ws;
    float* c0 = ws + KTOT * D;
    float* cc = c0 + D;
    if (bk < 128) {
        Wt[bk * D + d] = qw[d * 320 + bk];
    } else if (bk < 192) {
        const int e = bk - 128;
        const float4* qrow = (const float4*)(qw + d * 320 + 128);
        float s = 0.f;
        #pragma unroll
        for (int g = 0; g < 32; ++g) {
            float4 q = qrow[g];
            s = fmaf(q.x, ew[(4 * g + 0) * EDIM + e], s);
            s = fmaf(q.y, ew[(4 * g + 1) * EDIM + e], s);
            s = fmaf(q.z, ew[(4 * g + 2) * EDIM + e], s);
            s = fmaf(q.w, ew[(4 * g + 3) * EDIM + e], s);
        }
        Wt[bk * D + d] = s;
    } else if (bk < 256) {
        Wt[bk * D + d] = qw[d * 320 + 256 + (bk - 192)];
    } else if (bk == 256) {
        const float4* qrow = (const float4*)(qw + d * 320 + 128);
        const float4* eb4 = (const float4*)eb;
        float s = qb[d];
        #pragma unroll
        for (int g = 0; g < 32; ++g) {
            float4 q = qrow[g], e4 = eb4[g];
            s = fmaf(q.x, e4.x, s); s = fmaf(q.y, e4.y, s);
            s = fmaf(q.z, e4.z, s); s = fmaf(q.w, e4.w, s);
        }
        c0[d] = s;
    } else {
        if (d == 0) { float s = 0.f; for (int i = 0; i < D; ++i) s = fmaf(pg[i], pg[i], s); cc[0] = s; }
        if (d == 1) { float s = 0.f; for (int i = 0; i < D; ++i) s = fmaf(pg[i], pb[i], s); cc[1] = s; }
        if (d == 2) { float s = 0.f; for (int i = 0; i < D; ++i) s = fmaf(pb[i], pb[i], s); cc[2] = s; }
    }
}

// ---------------- K0b: pack Wt into split-bf16 MFMA B-fragments ----------------
// B[k][col]: lane l holds k = kb*32 + (l>>4)*8 + j, col = nt*16 + (l&15).
__global__ void k0b_pack(float* __restrict__ ws) {
    const int kb = blockIdx.x >> 3;
    const int nt = blockIdx.x & 7;
    const int l = threadIdx.x;    // 0..63
    const float* Wt = ws;
    const int colp = nt * 16 + (l & 15);
    const int kbase = kb * 32 + (l >> 4) * 8;
    bf16x8 hi, lo;
    #pragma unroll
    for (int j = 0; j < 8; ++j) {
        float x = Wt[(kbase + j) * D + colp];
        unsigned short h = bf16rne(x);
        hi[j] = (short)h;
        lo[j] = (short)bf16rne(x - bf16tof(h));
    }
    bf16x8* outp = (bf16x8*)(ws + WSB_OFF);
    outp[((kb * 8 + nt) * 2 + 0) * 64 + l] = hi;
    outp[((kb * 8 + nt) * 2 + 1) * 64 + l] = lo;
}

// ---------------- K_fused: MFMA GEMM (async-LDS dbuf B) + R9 epilogue ----------------
// A-side: element = lane&15, k = kb*32 + (lane>>4)*8 + j.
// C-side: element = (lane>>4)*4 + r, dims = {j*16 + (lane&15)} [m89].
__global__ __launch_bounds__(256, 3)
void k_fused(const int* __restrict__ nids, const float* __restrict__ ef,
             const float* __restrict__ tarr, const float* __restrict__ raw_mem,
             const float* __restrict__ protos,
             const float* __restrict__ pg, const float* __restrict__ pb,
             const float* __restrict__ tw, const float* __restrict__ tb,
             const float* __restrict__ cg, const float* __restrict__ cb,
             const float* __restrict__ gw, const float* __restrict__ gb,
             const float* __restrict__ temp, const float* __restrict__ ws,
             float* __restrict__ out, int Btot) {
    __shared__ bf16x8 Bs[2048];   // 32 KB double buffer: [buf(2)][i=nt*2+s][lane]
    __shared__ float cst[448];    // gwr[128] gwc[128] tw[64] tb[64] gwt[64]

    const int tid = threadIdx.x;
    const int lane = tid & 63;
    const int wave = tid >> 6;
    const int m0 = blockIdx.x * 64 + wave * 16;
    const int col = lane & 15;
    const int kg = lane >> 4;

    // ---- stage const table ----
    if (tid < 128) {
        cst[tid] = gw[tid];              // gwr
        cst[128 + tid] = gw[128 + tid];  // gwc
    } else {
        const int u = tid - 128;
        if (u < 64) { cst[256 + u] = tw[u]; cst[320 + u] = tb[u]; }
        else        { cst[384 + u - 64] = gw[256 + u - 64]; }
    }

    // ================= GEMM phase (A-side) =================
    const int elemA = min(m0 + col, Btot - 1);
    const int nidA = nids[elemA];
    const float* rawpA = raw_mem + (size_t)nidA * D + kg * 8;
    const float* efpA = ef + (size_t)elemA * EDIM + kg * 8;
    const float tvalA = tarr[elemA];
    const bf16x8* wbg = (const bf16x8*)(ws + WSB_OFF);

    f32x4 acc[8];
    #pragma unroll
    for (int nt = 0; nt < 8; ++nt) acc[nt] = (f32x4){0.f, 0.f, 0.f, 0.f};

    // async stage: B fragments kb -> Bs buffer (wave-uniform dst + lane*16)
#define STAGE_B(KB, BUF) { \
        const bf16x8* wn_ = wbg + (KB) * 1024; \
        __builtin_amdgcn_global_load_lds( \
            (const __attribute__((address_space(1))) unsigned int*)(wn_ + 0 * 256 + tid), \
            (__attribute__((address_space(3))) unsigned int*)&Bs[(BUF) + 0 * 256 + wave * 64], 16, 0, 0); \
        __builtin_amdgcn_global_load_lds( \
            (const __attribute__((address_space(1))) unsigned int*)(wn_ + 1 * 256 + tid), \
            (__attribute__((address_space(3))) unsigned int*)&Bs[(BUF) + 1 * 256 + wave * 64], 16, 0, 0); \
        __builtin_amdgcn_global_load_lds( \
            (const __attribute__((address_space(1))) unsigned int*)(wn_ + 2 * 256 + tid), \
            (__attribute__((address_space(3))) unsigned int*)&Bs[(BUF) + 2 * 256 + wave * 64], 16, 0, 0); \
        __builtin_amdgcn_global_load_lds( \
            (const __attribute__((address_space(1))) unsigned int*)(wn_ + 3 * 256 + tid), \
            (__attribute__((address_space(3))) unsigned int*)&Bs[(BUF) + 3 * 256 + wave * 64], 16, 0, 0); \
    }

    // prologue: stage kb0 into buf0; load A(kb0); barrier (drains vmcnt)
    STAGE_B(0, 0)
    v4f xa0 = *(const v4f*)rawpA;
    v4f xa1 = *(const v4f*)(rawpA + 4);
    __syncthreads();

    #pragma unroll 1
    for (int kb = 0; kb < 8; ++kb) {
        const int cur = (kb & 1) << 10;
        v4f xn0 = xa0, xn1 = xa1;
        if (kb < 7) {
            const int kn = kb + 1;
            STAGE_B(kn, cur ^ 1024)     // async into other buffer; in flight under MFMA
            if (kn < 4) {
                xn0 = *(const v4f*)(rawpA + kn * 32);
                xn1 = *(const v4f*)(rawpA + kn * 32 + 4);
            } else if (kn < 6) {
                xn0 = *(const v4f*)(efpA + (kn - 4) * 32);
                xn1 = *(const v4f*)(efpA + (kn - 4) * 32 + 4);
            } else {
                const int u0 = (kn - 6) * 32 + kg * 8;
                v4f wa = *(const v4f*)(tw + u0);
                v4f wb2 = *(const v4f*)(tw + u0 + 4);
                v4f ba = *(const v4f*)(tb + u0);
                v4f bb2 = *(const v4f*)(tb + u0 + 4);
                #pragma unroll
                for (int j = 0; j < 4; ++j) xn0[j] = __cosf(fmaf(tvalA, wa[j], ba[j]));
                #pragma unroll
                for (int j = 0; j < 4; ++j) xn1[j] = __cosf(fmaf(tvalA, wb2[j], bb2[j]));
            }
        }
        // split current A into hi/lo bf16 fragments
        bf16x8 ahi, alo;
        #pragma unroll
        for (int j = 0; j < 4; ++j) {
            unsigned short h = bf16rne(xa0[j]);
            ahi[j] = (short)h;
            alo[j] = (short)bf16rne(xa0[j] - bf16tof(h));
        }
        #pragma unroll
        for (int j = 0; j < 4; ++j) {
            unsigned short h = bf16rne(xa1[j]);
            ahi[4 + j] = (short)h;
            alo[4 + j] = (short)bf16rne(xa1[j] - bf16tof(h));
        }
        // 8 n-tiles × 3 split MFMAs, B from current LDS buffer
        #pragma unroll
        for (int nt = 0; nt < 8; ++nt) {
            bf16x8 bhi = Bs[cur + (nt * 2 + 0) * 64 + lane];
            bf16x8 blo = Bs[cur + (nt * 2 + 1) * 64 + lane];
            acc[nt] = __builtin_amdgcn_mfma_f32_16x16x32_bf16(ahi, bhi, acc[nt], 0, 0, 0);
            acc[nt] = __builtin_amdgcn_mfma_f32_16x16x32_bf16(ahi, blo, acc[nt], 0, 0, 0);
            acc[nt] = __builtin_amdgcn_mfma_f32_16x16x32_bf16(alo, bhi, acc[nt], 0, 0, 0);
        }
        // single barrier per kb: drains this wave's async loads (vmcnt0) + read fence
        if (kb < 7) __syncthreads();
        xa0 = xn0; xa1 = xn1;
    }

    // ================= epilogue phase (C-side, strided dims j*16+col) — R9 verbatim ====
    // fold c0 into acc
    {
        const float* c0 = ws + KTOT * D;
        #pragma unroll
        for (int j = 0; j < 8; ++j) {
            const float cv = c0[j * 16 + col];
            acc[j][0] += cv; acc[j][1] += cv; acc[j][2] += cv; acc[j][3] += cv;
        }
    }
    const float sbb = (ws + KTOT * D + D)[2];
    const float tempc = fminf(fmaxf(temp[0], 0.05f), 2.0f) + 1e-4f;
    const float its = 1.0f / tempc;
    const float gbias = gb[0];

    // hot per-dim constants in regs (32 VGPR)
    float pg8[8], pb8[8], cg8[8], cb8[8];
    #pragma unroll
    for (int j = 0; j < 8; ++j) {
        const int dd = j * 16 + col;
        pg8[j] = pg[dd]; pb8[j] = pb[dd];
        cg8[j] = cg[dd]; cb8[j] = cb[dd];
    }

    #pragma unroll
    for (int r = 0; r < 4; ++r) {
        const int erow = m0 + kg * 4 + r;
        const bool act = (erow < Btot);
        const int ebb = act ? erow : Btot - 1;
        const int nid = nids[ebb];
        const float* rawrow = raw_mem + (size_t)nid * D;
        const float* prow = protos + (size_t)nid * (NP * D);
        const float tval = tarr[ebb];

        float rawv[8], pxv[NP][8];
        #pragma unroll
        for (int j = 0; j < 8; ++j) rawv[j] = rawrow[j * 16 + col];
        #pragma unroll
        for (int p = 0; p < NP; ++p)
            #pragma unroll
            for (int j = 0; j < 8; ++j) pxv[p][j] = prow[p * D + j * 16 + col];

        float qv[8];
        #pragma unroll
        for (int j = 0; j < 8; ++j) qv[j] = acc[j][r];

        // ---- query = tanh(LN(q_pre)) (no memory dep; covers gathers above) ----
        float sx = 0.f;
        #pragma unroll
        for (int j = 0; j < 8; ++j) sx += qv[j];
        sx = qred16(sx);
        const float mu = sx * (1.f / D);
        float sv = 0.f;
        #pragma unroll
        for (int j = 0; j < 8; ++j) { float a = qv[j] - mu; sv = fmaf(a, a, sv); }
        sv = qred16(sv);
        const float rsq = __builtin_amdgcn_rsqf(sv * (1.f / D) + LN_EPS);

        float ssq = 0.f;
        #pragma unroll
        for (int j = 0; j < 8; ++j) {
            float x = fmaf((qv[j] - mu) * rsq, cg8[j], cb8[j]);
            float e2x = __expf(2.f * x);
            float th = 1.f - 2.f * __builtin_amdgcn_rcpf(e2x + 1.f);
            qv[j] = th;
            ssq = fmaf(th, th, ssq);
        }
        ssq = qred16(ssq);
        const float invq = __builtin_amdgcn_rcpf(fmaxf(sqrtf(ssq), 1e-6f));

        float aqg = 0.f, aqb = 0.f;
        #pragma unroll
        for (int j = 0; j < 8; ++j) {
            float qn = qv[j] * invq;
            float qg = qn * pg8[j];
            aqg += qg;
            aqb = fmaf(qn, pb8[j], aqb);
            qv[j] = qg;    // qv now holds qn*g
        }
        aqg = qred16(aqg);
        aqb = qred16(aqb);

        // ---- gate partials: raw share + te share (constants from LDS) ----
        float gsum = 0.f;
        {
            #pragma unroll
            for (int j = 0; j < 8; ++j)
                gsum = fmaf(cst[j * 16 + col], clipf(rawv[j], -100.f, 100.f), gsum);
            const v4f twc = *(const v4f*)&cst[256 + col * 4];
            const v4f tbc = *(const v4f*)&cst[320 + col * 4];
            const v4f gwt = *(const v4f*)&cst[384 + col * 4];
            #pragma unroll
            for (int j = 0; j < 4; ++j)
                gsum = fmaf(gwt[j], __cosf(fmaf(tval, twc[j], tbc[j])), gsum);
        }

        // ---- per-proto LN stats + cosine sim ----
        float mups[NP], rsps[NP], simv[NP];
        #pragma unroll
        for (int p = 0; p < NP; ++p) {
            float s_x = 0.f, sxx = 0.f, sqgx = 0.f;
            #pragma unroll
            for (int j = 0; j < 8; ++j) {
                float x = pxv[p][j];
                s_x += x;
                sxx = fmaf(x, x, sxx);
                sqgx = fmaf(qv[j], x, sqgx);
            }
            s_x = qred16(s_x); sxx = qred16(sxx); sqgx = qred16(sqgx);
            const float mup = s_x * (1.f / D);
            const float varp = sxx * (1.f / D) - mup * mup;
            const float rsp = __builtin_amdgcn_rsqf(varp + LN_EPS);
            float sz2 = 0.f, szb = 0.f;
            #pragma unroll
            for (int j = 0; j < 8; ++j) {
                float z = (pxv[p][j] - mup) * pg8[j];
                sz2 = fmaf(z, z, sz2);
                szb = fmaf(z, pb8[j], szb);
            }
            sz2 = qred16(sz2); szb = qred16(szb);
            const float dot = fmaf(rsp, sqgx - mup * aqg, aqb);
            float nrm2 = fmaf(rsp * rsp, sz2, fmaf(2.f * rsp, szb, sbb));
            nrm2 = fmaxf(nrm2, 0.f);
            const float inv = __builtin_amdgcn_rcpf(fmaxf(sqrtf(nrm2), 1e-6f));
            mups[p] = mup;
            rsps[p] = rsp;
            simv[p] = clipf(dot * inv, -30.f, 30.f) * its;
        }

        // ---- softmax over 5 ----
        float mx = fmaxf(fmaxf(fmaxf(simv[0], simv[1]), fmaxf(simv[2], simv[3])), simv[4]);
        float wp[NP];
        float Z = 0.f;
        #pragma unroll
        for (int p = 0; p < NP; ++p) { float ev = __expf(simv[p] - mx); wp[p] = ev; Z += ev; }
        const float iZ = 1.f / Z;
        float a0 = 0.f, a1 = 0.f;
        #pragma unroll
        for (int p = 0; p < NP; ++p) {
            float at = wp[p] * iZ;
            a0 += at;
            float w = at * rsps[p];
            a1 = fmaf(w, mups[p], a1);
            wp[p] = w;
        }

        // ---- weighted proto sum, cand, gate ----
        float S8[8];
        #pragma unroll
        for (int j = 0; j < 8; ++j) S8[j] = 0.f;
        #pragma unroll
        for (int p = 0; p < NP; ++p) {
            #pragma unroll
            for (int j = 0; j < 8; ++j) S8[j] = fmaf(wp[p], pxv[p][j], S8[j]);
        }
        float gc = gsum;
        #pragma unroll
        for (int j = 0; j < 8; ++j) {
            float cnd = clipf(fmaf(pg8[j], S8[j] - a1, pb8[j] * a0), -5.f, 5.f);
            gc = fmaf(cst[128 + j * 16 + col], cnd, gc);
            S8[j] = cnd;
        }
        gc = qred16(gc);
        const float gpre = gc + gbias;
        const float gate = __builtin_amdgcn_rcpf(1.f + __expf(-gpre));

        // ---- blend, LN, clip, store ----
        float su = 0.f, ssu = 0.f;
        #pragma unroll
        for (int j = 0; j < 8; ++j) {
            float u = fmaf(gate, S8[j] - rawv[j], rawv[j]);
            S8[j] = u;
            su += u;
            ssu = fmaf(u, u, ssu);
        }
        su = qred16(su);
        ssu = qred16(ssu);
        const float muu = su * (1.f / D);
        const float varu = ssu * (1.f / D) - muu * muu;
        const float rsu = __builtin_amdgcn_rsqf(varu + LN_EPS);

        if (act) {
            float* orow = out + (size_t)erow * D;
            #pragma unroll
            for (int j = 0; j < 8; ++j) {
                orow[j * 16 + col] = clipf(fmaf((S8[j] - muu) * rsu, cg8[j], cb8[j]), -10.f, 10.f);
            }
        }
    }
}

extern "C" void kernel_launch(void* const* d_in, const int* in_sizes, int n_in,
                              void* d_out, int out_size, void* d_ws, size_t ws_size,
                              hipStream_t stream) {
    const int*   nids = (const int*)d_in[0];
    const float* ef   = (const float*)d_in[1];
    const float* t    = (const float*)d_in[2];
    const float* raw  = (const float*)d_in[3];
    const float* prot = (const float*)d_in[4];
    const float* pg   = (const float*)d_in[5];
    const float* pb   = (const float*)d_in[6];
    const float* tw   = (const float*)d_in[7];
    const float* tb   = (const float*)d_in[8];
    const float* ew   = (const float*)d_in[9];
    const float* eb   = (const float*)d_in[10];
    const float* qw   = (const float*)d_in[11];
    const float* qb   = (const float*)d_in[12];
    const float* cg   = (const float*)d_in[13];
    const float* cb   = (const float*)d_in[14];
    const float* gw   = (const float*)d_in[15];
    const float* gb   = (const float*)d_in[16];
    const float* temp = (const float*)d_in[17];
    float* ws  = (float*)d_ws;
    float* out = (float*)d_out;
    const int Btot = in_sizes[0];

    hipLaunchKernelGGL(k0_fold, dim3(258), dim3(128), 0, stream,
                       qw, qb, ew, eb, pg, pb, ws);
    hipLaunchKernelGGL(k0b_pack, dim3(64), dim3(64), 0, stream, ws);
    hipLaunchKernelGGL(k_fused, dim3((Btot + 63) / 64), dim3(256), 0, stream,
                       nids, ef, t, raw, prot, pg, pb, tw, tb, cg, cb, gw, gb, temp, ws, out, Btot);
}

// Round 15
// 120.932 us; speedup vs baseline: 1.0404x; 1.0404x over previous
//
#include <hip/hip_runtime.h>

#define D 128
#define EDIM 64
#define TDIM 64
#define KTOT 256
#define NP 5
#define LN_EPS 1e-4f
#define WSB_OFF 33024   // float offset of bf16 B-fragments in ws

typedef float v4f __attribute__((ext_vector_type(4)));
typedef float f32x4 __attribute__((ext_vector_type(4)));
typedef short bf16x8 __attribute__((ext_vector_type(8)));

__device__ __forceinline__ float clipf(float x, float lo, float hi) {
    return fminf(fmaxf(x, lo), hi);
}

__device__ __forceinline__ unsigned short bf16rne(float x) {
    unsigned int u = __float_as_uint(x);
    unsigned int r = (u + 0x7fffu + ((u >> 16) & 1u)) >> 16;
    return (unsigned short)r;
}
__device__ __forceinline__ float bf16tof(unsigned short h) {
    return __uint_as_float(((unsigned int)h) << 16);
}

// sum across each 16-lane DPP row — pure-VALU DPP reduction.
template <int CTRL>
__device__ __forceinline__ float dpp_addstep(float v) {
    int o = __builtin_amdgcn_update_dpp(0, __float_as_int(v), CTRL, 0xF, 0xF, true);
    return v + __int_as_float(o);
}
__device__ __forceinline__ float qred16(float v) {
    v = dpp_addstep<0xB1>(v);    // quad_perm xor 1
    v = dpp_addstep<0x4E>(v);    // quad_perm xor 2
    v = dpp_addstep<0x124>(v);   // row_ror:4
    v = dpp_addstep<0x128>(v);   // row_ror:8
    return v;
}

// ---------------- K0: fold weights into ws ----------------
// ws layout (floats): Wt[256*128] (k-major), c0[128], cc[3]={sgg,sgb,sbb},
// then at WSB_OFF: bf16x8 B-fragments [kb(8)][nt(8)][s(2)][lane(64)].
__global__ void k0_fold(const float* __restrict__ qw, const float* __restrict__ qb,
                        const float* __restrict__ ew, const float* __restrict__ eb,
                        const float* __restrict__ pg, const float* __restrict__ pb,
                        float* __restrict__ ws) {
    const int d = threadIdx.x;   // 0..127
    const int bk = blockIdx.x;   // 0..257
    float* Wt = ws;
    float* c0 = ws + KTOT * D;
    float* cc = c0 + D;
    if (bk < 128) {
        Wt[bk * D + d] = qw[d * 320 + bk];
    } else if (bk < 192) {
        const int e = bk - 128;
        const float4* qrow = (const float4*)(qw + d * 320 + 128);
        float s = 0.f;
        #pragma unroll
        for (int g = 0; g < 32; ++g) {
            float4 q = qrow[g];
            s = fmaf(q.x, ew[(4 * g + 0) * EDIM + e], s);
            s = fmaf(q.y, ew[(4 * g + 1) * EDIM + e], s);
            s = fmaf(q.z, ew[(4 * g + 2) * EDIM + e], s);
            s = fmaf(q.w, ew[(4 * g + 3) * EDIM + e], s);
        }
        Wt[bk * D + d] = s;
    } else if (bk < 256) {
        Wt[bk * D + d] = qw[d * 320 + 256 + (bk - 192)];
    } else if (bk == 256) {
        const float4* qrow = (const float4*)(qw + d * 320 + 128);
        const float4* eb4 = (const float4*)eb;
        float s = qb[d];
        #pragma unroll
        for (int g = 0; g < 32; ++g) {
            float4 q = qrow[g], e4 = eb4[g];
            s = fmaf(q.x, e4.x, s); s = fmaf(q.y, e4.y, s);
            s = fmaf(q.z, e4.z, s); s = fmaf(q.w, e4.w, s);
        }
        c0[d] = s;
    } else {
        if (d == 0) { float s = 0.f; for (int i = 0; i < D; ++i) s = fmaf(pg[i], pg[i], s); cc[0] = s; }
        if (d == 1) { float s = 0.f; for (int i = 0; i < D; ++i) s = fmaf(pg[i], pb[i], s); cc[1] = s; }
        if (d == 2) { float s = 0.f; for (int i = 0; i < D; ++i) s = fmaf(pb[i], pb[i], s); cc[2] = s; }
    }
}

// ---------------- K0b: pack Wt into split-bf16 MFMA B-fragments ----------------
// B[k][col]: lane l holds k = kb*32 + (l>>4)*8 + j, col = nt*16 + (l&15).
__global__ void k0b_pack(float* __restrict__ ws) {
    const int kb = blockIdx.x >> 3;
    const int nt = blockIdx.x & 7;
    const int l = threadIdx.x;    // 0..63
    const float* Wt = ws;
    const int col = nt * 16 + (l & 15);
    const int kbase = kb * 32 + (l >> 4) * 8;
    bf16x8 hi, lo;
    #pragma unroll
    for (int j = 0; j < 8; ++j) {
        float x = Wt[(kbase + j) * D + col];
        unsigned short h = bf16rne(x);
        hi[j] = (short)h;
        lo[j] = (short)bf16rne(x - bf16tof(h));
    }
    bf16x8* outp = (bf16x8*)(ws + WSB_OFF);
    outp[((kb * 8 + nt) * 2 + 0) * 64 + l] = hi;
    outp[((kb * 8 + nt) * 2 + 1) * 64 + l] = lo;
}

// ---------------- K_fused: MFMA GEMM (B via shared LDS tile) + full epilogue ----
// Per wave: one 16-elem m-tile.
// A-side: element = lane&15, k = kb*32 + (lane>>4)*8 + j  (matches k0b pack).
// C-side: element = (lane>>4)*4 + r, dims = {j*16 + (lane&15) : j=0..7} [m89].
__global__ __launch_bounds__(256, 3)
void k_fused(const int* __restrict__ nids, const float* __restrict__ ef,
             const float* __restrict__ tarr, const float* __restrict__ raw_mem,
             const float* __restrict__ protos,
             const float* __restrict__ pg, const float* __restrict__ pb,
             const float* __restrict__ tw, const float* __restrict__ tb,
             const float* __restrict__ cg, const float* __restrict__ cb,
             const float* __restrict__ gw, const float* __restrict__ gb,
             const float* __restrict__ temp, const float* __restrict__ ws,
             float* __restrict__ out, int Btot) {
    __shared__ bf16x8 Bs[1024];   // 16 KB: [i = nt*2+s][lane] per current kb
    __shared__ float cst[448];    // gwr[128] gwc[128] tw[64] tb[64] gwt[64]

    const int tid = threadIdx.x;
    const int lane = tid & 63;
    const int wave = tid >> 6;
    const int m0 = blockIdx.x * 64 + wave * 16;
    const int col = lane & 15;
    const int kg = lane >> 4;

    // ---- stage const table ----
    if (tid < 128) {
        cst[tid] = gw[tid];              // gwr
        cst[128 + tid] = gw[128 + tid];  // gwc
    } else {
        const int u = tid - 128;
        if (u < 64) { cst[256 + u] = tw[u]; cst[320 + u] = tb[u]; }
        else        { cst[384 + u - 64] = gw[256 + u - 64]; }
    }

    // ================= GEMM phase (A-side) =================
    const int elemA = min(m0 + col, Btot - 1);
    const int nidA = nids[elemA];
    const float* rawpA = raw_mem + (size_t)nidA * D + kg * 8;
    const float* efpA = ef + (size_t)elemA * EDIM + kg * 8;
    const float tvalA = tarr[elemA];
    const bf16x8* wbg = (const bf16x8*)(ws + WSB_OFF);

    f32x4 acc[8];
    #pragma unroll
    for (int nt = 0; nt < 8; ++nt) acc[nt] = (f32x4){0.f, 0.f, 0.f, 0.f};

    {
        // prefetch kb=0
        bf16x8 s0 = wbg[tid], s1 = wbg[256 + tid], s2 = wbg[512 + tid], s3 = wbg[768 + tid];
        v4f xa0 = *(const v4f*)rawpA;
        v4f xa1 = *(const v4f*)(rawpA + 4);

        #pragma unroll 1
        for (int kb = 0; kb < 8; ++kb) {
            __syncthreads();
            Bs[tid] = s0; Bs[256 + tid] = s1; Bs[512 + tid] = s2; Bs[768 + tid] = s3;
            __syncthreads();
            v4f xn0 = xa0, xn1 = xa1;
            if (kb < 7) {
                const int kn = kb + 1;
                const bf16x8* wn = wbg + kn * 1024;
                s0 = wn[tid]; s1 = wn[256 + tid]; s2 = wn[512 + tid]; s3 = wn[768 + tid];
                if (kn < 4) {
                    xn0 = *(const v4f*)(rawpA + kn * 32);
                    xn1 = *(const v4f*)(rawpA + kn * 32 + 4);
                } else if (kn < 6) {
                    xn0 = *(const v4f*)(efpA + (kn - 4) * 32);
                    xn1 = *(const v4f*)(efpA + (kn - 4) * 32 + 4);
                } else {
                    const int u0 = (kn - 6) * 32 + kg * 8;
                    v4f wa = *(const v4f*)(tw + u0);
                    v4f wb2 = *(const v4f*)(tw + u0 + 4);
                    v4f ba = *(const v4f*)(tb + u0);
                    v4f bb2 = *(const v4f*)(tb + u0 + 4);
                    #pragma unroll
                    for (int j = 0; j < 4; ++j) xn0[j] = __cosf(fmaf(tvalA, wa[j], ba[j]));
                    #pragma unroll
                    for (int j = 0; j < 4; ++j) xn1[j] = __cosf(fmaf(tvalA, wb2[j], bb2[j]));
                }
            }
            bf16x8 ahi, alo;
            #pragma unroll
            for (int j = 0; j < 4; ++j) {
                unsigned short h = bf16rne(xa0[j]);
                ahi[j] = (short)h;
                alo[j] = (short)bf16rne(xa0[j] - bf16tof(h));
            }
            #pragma unroll
            for (int j = 0; j < 4; ++j) {
                unsigned short h = bf16rne(xa1[j]);
                ahi[4 + j] = (short)h;
                alo[4 + j] = (short)bf16rne(xa1[j] - bf16tof(h));
            }
            #pragma unroll
            for (int nt = 0; nt < 8; ++nt) {
                bf16x8 bhi = Bs[(nt * 2 + 0) * 64 + lane];
                bf16x8 blo = Bs[(nt * 2 + 1) * 64 + lane];
                acc[nt] = __builtin_amdgcn_mfma_f32_16x16x32_bf16(ahi, bhi, acc[nt], 0, 0, 0);
                acc[nt] = __builtin_amdgcn_mfma_f32_16x16x32_bf16(ahi, blo, acc[nt], 0, 0, 0);
                acc[nt] = __builtin_amdgcn_mfma_f32_16x16x32_bf16(alo, bhi, acc[nt], 0, 0, 0);
            }
            xa0 = xn0; xa1 = xn1;
        }
    }

    // ================= epilogue phase (C-side) =================
    // fold c0 into acc once
    {
        const float* c0 = ws + KTOT * D;
        #pragma unroll
        for (int j = 0; j < 8; ++j) {
            const float cv = c0[j * 16 + col];
            acc[j][0] += cv; acc[j][1] += cv; acc[j][2] += cv; acc[j][3] += cv;
        }
    }
    const float sbb = (ws + KTOT * D + D)[2];
    const float tempc = fminf(fmaxf(temp[0], 0.05f), 2.0f) + 1e-4f;
    const float its = 1.0f / tempc;
    const float gbias = gb[0];

    // hot per-dim constants in regs
    float pg8[8], pb8[8], cg8[8], cb8[8];
    #pragma unroll
    for (int j = 0; j < 8; ++j) {
        const int dd = j * 16 + col;
        pg8[j] = pg[dd]; pb8[j] = pb[dd];
        cg8[j] = cg[dd]; cb8[j] = cb[dd];
    }

    #pragma unroll
    for (int r = 0; r < 4; ++r) {
        const int erow = m0 + kg * 4 + r;
        const bool act = (erow < Btot);
        const int ebb = act ? erow : Btot - 1;
        const int nid = nids[ebb];
        const float* rawrow = raw_mem + (size_t)nid * D;
        const float* prow = protos + (size_t)nid * (NP * D);
        const float tval = tarr[ebb];

        float qv[8], rawv[8];
        #pragma unroll
        for (int j = 0; j < 8; ++j) {
            qv[j] = acc[j][r];
            rawv[j] = rawrow[j * 16 + col];
        }
        float pxv[NP][8];
        #pragma unroll
        for (int p = 0; p < NP; ++p) {
            #pragma unroll
            for (int j = 0; j < 8; ++j) pxv[p][j] = prow[p * D + j * 16 + col];
        }

        // gate partials: raw share (8 dims) + te share (4 dims)
        float gsum = 0.f;
        #pragma unroll
        for (int j = 0; j < 8; ++j)
            gsum = fmaf(cst[j * 16 + col], clipf(rawv[j], -100.f, 100.f), gsum);
        #pragma unroll
        for (int j = 0; j < 4; ++j) {
            const int u = col * 4 + j;
            gsum = fmaf(cst[384 + u], __cosf(fmaf(tval, cst[256 + u], cst[320 + u])), gsum);
        }

        // ---- query = tanh(LN(q_pre)) ----
        float sx = 0.f;
        #pragma unroll
        for (int j = 0; j < 8; ++j) sx += qv[j];
        sx = qred16(sx);
        const float mu = sx * (1.f / D);
        float sv = 0.f;
        #pragma unroll
        for (int j = 0; j < 8; ++j) { float a = qv[j] - mu; sv = fmaf(a, a, sv); }
        sv = qred16(sv);
        const float rsq = __builtin_amdgcn_rsqf(sv * (1.f / D) + LN_EPS);

        float ssq = 0.f;
        #pragma unroll
        for (int j = 0; j < 8; ++j) {
            float x = fmaf((qv[j] - mu) * rsq, cg8[j], cb8[j]);
            float e2x = __expf(2.f * x);
            float th = 1.f - 2.f * __builtin_amdgcn_rcpf(e2x + 1.f);
            qv[j] = th;
            ssq = fmaf(th, th, ssq);
        }
        ssq = qred16(ssq);
        const float invq = __builtin_amdgcn_rcpf(fmaxf(sqrtf(ssq), 1e-6f));

        float aqg = 0.f, aqb = 0.f;
        #pragma unroll
        for (int j = 0; j < 8; ++j) {
            float qn = qv[j] * invq;
            float qg = qn * pg8[j];
            aqg += qg;
            aqb = fmaf(qn, pb8[j], aqb);
            qv[j] = qg;    // qv now holds qn*g
        }
        aqg = qred16(aqg);
        aqb = qred16(aqb);

        // ---- per-proto LN stats + cosine sim ----
        float mups[NP], rsps[NP], simv[NP];
        #pragma unroll
        for (int p = 0; p < NP; ++p) {
            float s_x = 0.f, sxx = 0.f, sqgx = 0.f;
            #pragma unroll
            for (int j = 0; j < 8; ++j) {
                float x = pxv[p][j];
                s_x += x;
                sxx = fmaf(x, x, sxx);
                sqgx = fmaf(qv[j], x, sqgx);
            }
            s_x = qred16(s_x); sxx = qred16(sxx); sqgx = qred16(sqgx);
            const float mup = s_x * (1.f / D);
            const float varp = sxx * (1.f / D) - mup * mup;
            const float rsp = __builtin_amdgcn_rsqf(varp + LN_EPS);
            float sz2 = 0.f, szb = 0.f;
            #pragma unroll
            for (int j = 0; j < 8; ++j) {
                float z = (pxv[p][j] - mup) * pg8[j];
                sz2 = fmaf(z, z, sz2);
                szb = fmaf(z, pb8[j], szb);
            }
            sz2 = qred16(sz2); szb = qred16(szb);
            const float dot = fmaf(rsp, sqgx - mup * aqg, aqb);
            float nrm2 = fmaf(rsp * rsp, sz2, fmaf(2.f * rsp, szb, sbb));
            nrm2 = fmaxf(nrm2, 0.f);
            const float inv = __builtin_amdgcn_rcpf(fmaxf(sqrtf(nrm2), 1e-6f));
            mups[p] = mup;
            rsps[p] = rsp;
            simv[p] = clipf(dot * inv, -30.f, 30.f) * its;
        }

        // ---- softmax over 5 ----
        float mx = fmaxf(fmaxf(fmaxf(simv[0], simv[1]), fmaxf(simv[2], simv[3])), simv[4]);
        float wp[NP];
        float Z = 0.f;
        #pragma unroll
        for (int p = 0; p < NP; ++p) { float ev = __expf(simv[p] - mx); wp[p] = ev; Z += ev; }
        const float iZ = 1.f / Z;
        float a0 = 0.f, a1 = 0.f;
        #pragma unroll
        for (int p = 0; p < NP; ++p) {
            float at = wp[p] * iZ;
            a0 += at;
            float w = at * rsps[p];
            a1 = fmaf(w, mups[p], a1);
            wp[p] = w;
        }

        // ---- weighted proto sum, cand, gate ----
        float S8[8];
        #pragma unroll
        for (int j = 0; j < 8; ++j) S8[j] = 0.f;
        #pragma unroll
        for (int p = 0; p < NP; ++p) {
            #pragma unroll
            for (int j = 0; j < 8; ++j) S8[j] = fmaf(wp[p], pxv[p][j], S8[j]);
        }
        float gc = gsum;
        #pragma unroll
        for (int j = 0; j < 8; ++j) {
            float cnd = clipf(fmaf(pg8[j], S8[j] - a1, pb8[j] * a0), -5.f, 5.f);
            gc = fmaf(cst[128 + j * 16 + col], cnd, gc);
            S8[j] = cnd;
        }
        gc = qred16(gc);
        const float gpre = gc + gbias;
        const float gate = __builtin_amdgcn_rcpf(1.f + __expf(-gpre));

        // ---- blend, LN, clip, store ----
        float su = 0.f, ssu = 0.f;
        #pragma unroll
        for (int j = 0; j < 8; ++j) {
            float u = fmaf(gate, S8[j] - rawv[j], rawv[j]);
            S8[j] = u;
            su += u;
            ssu = fmaf(u, u, ssu);
        }
        su = qred16(su);
        ssu = qred16(ssu);
        const float muu = su * (1.f / D);
        const float varu = ssu * (1.f / D) - muu * muu;
        const float rsu = __builtin_amdgcn_rsqf(varu + LN_EPS);

        if (act) {
            float* orow = out + (size_t)erow * D;
            #pragma unroll
            for (int j = 0; j < 8; ++j) {
                orow[j * 16 + col] = clipf(fmaf((S8[j] - muu) * rsu, cg8[j], cb8[j]), -10.f, 10.f);
            }
        }
    }
}

extern "C" void kernel_launch(void* const* d_in, const int* in_sizes, int n_in,
                              void* d_out, int out_size, void* d_ws, size_t ws_size,
                              hipStream_t stream) {
    const int*   nids = (const int*)d_in[0];
    const float* ef   = (const float*)d_in[1];
    const float* t    = (const float*)d_in[2];
    const float* raw  = (const float*)d_in[3];
    const float* prot = (const float*)d_in[4];
    const float* pg   = (const float*)d_in[5];
    const float* pb   = (const float*)d_in[6];
    const float* tw   = (const float*)d_in[7];
    const float* tb   = (const float*)d_in[8];
    const float* ew   = (const float*)d_in[9];
    const float* eb   = (const float*)d_in[10];
    const float* qw   = (const float*)d_in[11];
    const float* qb   = (const float*)d_in[12];
    const float* cg   = (const float*)d_in[13];
    const float* cb   = (const float*)d_in[14];
    const float* gw   = (const float*)d_in[15];
    const float* gb   = (const float*)d_in[16];
    const float* temp = (const float*)d_in[17];
    float* ws  = (float*)d_ws;
    float* out = (float*)d_out;
    const int Btot = in_sizes[0];

    hipLaunchKernelGGL(k0_fold, dim3(258), dim3(128), 0, stream,
                       qw, qb, ew, eb, pg, pb, ws);
    hipLaunchKernelGGL(k0b_pack, dim3(64), dim3(64), 0, stream, ws);
    hipLaunchKernelGGL(k_fused, dim3((Btot + 63) / 64), dim3(256), 0, stream,
                       nids, ef, t, raw, prot, pg, pb, tw, tb, cg, cb, gw, gb, temp, ws, out, Btot);
}